// Round 4
// baseline (297.791 us; speedup 1.0000x reference)
//
#include <hip/hip_runtime.h>

#define DIN   2048
#define DOUT  2048
#define NP    16
#define TPW   4    // tokens per wave
#define WPB   4    // waves per block

// ws layout (byte offsets)
#define HDR_OFF   0                      // 2 floats: w1, w2
#define WK4_OFF   256                    // 8192 u32 (32 KB) ternary Wk
#define WV4_OFF   (WK4_OFF + 32768)      // 2048 uint4 (32 KB) ternary Wv (transposed order)

static __device__ __forceinline__ int dot4(unsigned a, unsigned b, int c) {
#if defined(__has_builtin) && __has_builtin(__builtin_amdgcn_sdot4)
  return __builtin_amdgcn_sdot4((int)a, (int)b, c, false);
#else
  c += (int)(signed char)(a & 0xffu)        * (int)(signed char)(b & 0xffu);
  c += (int)(signed char)((a >> 8) & 0xffu) * (int)(signed char)((b >> 8) & 0xffu);
  c += (int)(signed char)((a >> 16) & 0xffu)* (int)(signed char)((b >> 16) & 0xffu);
  c += (int)(signed char)(a >> 24)          * (int)(signed char)(b >> 24);
  return c;
#endif
}

// fma-magic int8 quantize: low byte of (f*xs + 1.5*2^23) = round-to-even(f*xs)
static __device__ __forceinline__ unsigned qmagic(float f, float xs) {
  return __float_as_uint(fmaf(f, xs, 12582912.0f)) & 0xffu;
}

// reference-exact double-rounded quantize (epilogue 16-value re-quant)
static __device__ __forceinline__ unsigned q8(float f, float xs) {
  float t = f * xs;
  float r = rintf(t);
  r = fmaxf(-128.0f, fminf(127.0f, r));
  return ((unsigned)(int)r) & 0xffu;
}

// ---------------------------------------------------------------------------
// k_prep: fused reduce+pack, 40 blocks. Scale computation has the SAME op
// order as always -> bitwise-identical sc. Blocks 0-31 pack Wk (flat order),
// 32-39 pack Wv rows directly into the phase-B transposed layout:
//   wv4t[(m*4+j)*64 + lr] = row o, where o = m*256 + lr*4 + j
// so phase B's lane l reads consecutive uint4 (coalesced, L2-hot).
// ---------------------------------------------------------------------------
__global__ __launch_bounds__(256) void k_prep(
    const float* __restrict__ Wk, const float* __restrict__ Wv,
    float* __restrict__ hdr, unsigned* __restrict__ wk4, unsigned* __restrict__ wv4)
{
  __shared__ float red[8][256];
  const int tid = threadIdx.x, b = blockIdx.x;
  const int isV = (b >= 32);
  const float4* W = (const float4*)(isV ? Wv : Wk);

  float4 own = make_float4(0.f, 0.f, 0.f, 0.f);
#pragma unroll
  for (int lb = 0; lb < 8; ++lb) {
    float s = 0.f;
#pragma unroll
    for (int i = 0; i < 4; ++i) {
      float4 v = W[lb * 1024 + i * 256 + tid];
      if (!isV && (lb * 4 + i) == b) own = v;   // capture own pack slice
      s += fabsf(v.x) + fabsf(v.y) + fabsf(v.z) + fabsf(v.w);
    }
    red[lb][tid] = s;
  }
  __syncthreads();
#pragma unroll 1
  for (int o = 128; o > 0; o >>= 1) {
    if (tid < o) {
#pragma unroll
      for (int lb = 0; lb < 8; ++lb) red[lb][tid] += red[lb][tid + o];
    }
    __syncthreads();
  }
  float sum = 0.f;
#pragma unroll
  for (int lb = 0; lb < 8; ++lb) sum += red[lb][0];
  const float sc = fmaxf(sum * (1.0f / 32768.0f), 1e-5f);
  if (tid == 0 && (b == 0 || b == 32)) hdr[isV] = sc;

  if (!isV) {
    const int c = b * 256 + tid;          // [0, 8192)
    unsigned pk = 0; const float* wp = &own.x;
#pragma unroll
    for (int j = 0; j < 4; ++j) {
      float r = rintf(wp[j] / sc);
      r = fmaxf(-1.0f, fminf(1.0f, r));
      pk |= (((unsigned)(int)r) & 0xffu) << (8 * j);
    }
    wk4[c] = pk;
  } else {
    const int o = (b - 32) * 256 + tid;   // row [0, 2048)
    unsigned u[4];
#pragma unroll
    for (int cc = 0; cc < 4; ++cc) {
      float4 w = ((const float4*)Wv)[o * 4 + cc];   // L2-hot re-read
      const float* wp = &w.x;
      unsigned pk = 0;
#pragma unroll
      for (int r = 0; r < 4; ++r) {
        float q = rintf(wp[r] / sc);
        q = fmaxf(-1.0f, fminf(1.0f, q));
        pk |= (((unsigned)(int)q) & 0xffu) << (8 * r);
      }
      u[cc] = pk;
    }
    const int m = o >> 8, r = o & 255, lr = r >> 2, j = r & 3;
    ((uint4*)wv4)[(m * 4 + j) * 64 + lr] = make_uint4(u[0], u[1], u[2], u[3]);
  }
}

// ---------------------------------------------------------------------------
// k_main v4. Rounds 1-3 lesson: time (85 us) and VALUBusy (17%) were
// INVARIANT under register/remat/LDS weight storage -> the bottleneck is not
// data-side. All variants shared ~70 KB of fully-unrolled code (>> 32 KB L1I)
// and only 8 waves/CU. This version:
//   * rolled token loop (TPW=4), per-token epilogue: the old 4-token routing
//     only reordered INTEGER adds -> replaced by 2 extra shfl_xor int adds
//     (bitwise identical); all lanes compute the float epilogue redundantly
//     with identical values and identical reduction trees.
//   * rolled phase-B m-loop, rolled LDS fill -> total code ~6-8 KB << L1I.
//   * Wk in LDS (32 KB, b128 conflict-free both fill and read); Wv read
//     straight from L2 via pre-transposed wv4t (coalesced) -> LDS 33 KB,
//     4 blocks/CU; __launch_bounds__(256,4) caps VGPR at 128 (working set
//     ~100) -> 16 waves/CU, grid 1024 = exactly 4 blocks/CU.
//   * q2/s2 handoff via 320 B wave-private LDS (static reg indexing, rule #20).
// ---------------------------------------------------------------------------
__global__ __launch_bounds__(256, 4) void k_main(
    const float* __restrict__ x, const float* __restrict__ hdr,
    const unsigned* __restrict__ wk4, const unsigned* __restrict__ wv4t,
    float* __restrict__ out)
{
  const int tid = threadIdx.x;
  const int l   = tid & 63;
  const int ws  = tid >> 6;
  const long t0 = ((long)blockIdx.x * WPB + ws) * TPW;

  __shared__ uint4 wkL[2048];        // 32 KB ternary Wk: [p][half][lane]
  __shared__ uint4 qls[WPB][TPW];    // per-wave q2 handoff
  __shared__ float sls[WPB][TPW];    // per-wave s2 handoff

  const float w1 = hdr[0], w2 = hdr[1];
  const float4* xf  = (const float4*)x;
  const uint4*  wvt = (const uint4*)wv4t;

  // ---- cooperative wkL fill: dest uint4 d = p*128 + half*64 + lane
  //      <- src words p*512 + (half*4 + k)*64 + lane, k=0..3.
  //      Global loads coalesced; ds_write_b128 contiguous (conflict-free). ----
#pragma unroll 1
  for (int r = 0; r < 8; ++r) {
    const int d = r * 256 + tid;
    const int p = d >> 7, half = (d >> 6) & 1, lg = d & 63;
    const int s = p * 512 + half * 256 + lg;
    wkL[d] = make_uint4(wk4[s], wk4[s + 64], wk4[s + 128], wk4[s + 192]);
  }
  __syncthreads();

  // ---- phase A: rolled over tokens ----
#pragma unroll 1
  for (int t = 0; t < TPW; ++t) {
    const long tok = t0 + t;

    float4 a[8];
#pragma unroll
    for (int c = 0; c < 8; ++c) a[c] = xf[tok * 512 + c * 64 + l];

    // absmax over this token (full wave) — same tree as always
    float mx = 0.0f;
#pragma unroll
    for (int c = 0; c < 8; ++c) {
      mx = fmaxf(mx, fabsf(a[c].x)); mx = fmaxf(mx, fabsf(a[c].y));
      mx = fmaxf(mx, fabsf(a[c].z)); mx = fmaxf(mx, fabsf(a[c].w));
    }
#pragma unroll
    for (int d = 1; d < 64; d <<= 1) mx = fmaxf(mx, __shfl_xor(mx, d, 64));
    const float mcl = fmaxf(mx, 1e-5f);
    const float xs  = 127.0f / mcl;
    const float s1  = w1 / xs;

    // quantize (|f*xs| <= 127 exactly, no clamp needed)
    unsigned qp[8];
#pragma unroll
    for (int c = 0; c < 8; ++c) {
      qp[c] = qmagic(a[c].x, xs) | (qmagic(a[c].y, xs) << 8)
            | (qmagic(a[c].z, xs) << 16) | (qmagic(a[c].w, xs) << 24);
    }

    // 16 integer dot rows from LDS (2x ds_read_b128 per p)
    int acc[16];
#pragma unroll
    for (int p = 0; p < 16; ++p) {
      const uint4 w0 = wkL[p * 128 + l];        // c = 0..3
      const uint4 w4 = wkL[p * 128 + 64 + l];   // c = 4..7
      int d = 0;
      d = dot4(qp[0], w0.x, d); d = dot4(qp[1], w0.y, d);
      d = dot4(qp[2], w0.z, d); d = dot4(qp[3], w0.w, d);
      d = dot4(qp[4], w4.x, d); d = dot4(qp[5], w4.y, d);
      d = dot4(qp[6], w4.z, d); d = dot4(qp[7], w4.w, d);
      acc[p] = d;
    }

    // recursive-halving reduce-scatter, identity perm (p = l&15)
#pragma unroll
    for (int b = 0; b < 4; ++b) {
      const int lb = (l >> b) & 1;
#pragma unroll
      for (int j = 0; j < 8; ++j) {
        if (j < (8 >> b)) {
          int keep = lb ? acc[2 * j + 1] : acc[2 * j];
          int send = lb ? acc[2 * j]     : acc[2 * j + 1];
          acc[j] = keep + __shfl_xor(send, 1 << b, 64);
        }
      }
    }
    // finish: sum the 4 quarter-partials (int adds -> order-exact)
    int rr = acc[0];
    rr += __shfl_xor(rr, 16, 64);
    rr += __shfl_xor(rr, 32, 64);

    // ---- per-token epilogue, all lanes redundant (p = l&15) ----
    const float fa = (float)rr * s1;
    const float gv = 0.5f * fa * (1.0f + erff(fa * 0.70710678118654752f));
    float ss = gv * gv;
    ss += __shfl_xor(ss, 1, 64); ss += __shfl_xor(ss, 2, 64);
    ss += __shfl_xor(ss, 4, 64); ss += __shfl_xor(ss, 8, 64);
    const float rn = fmaxf(sqrtf(ss), 1e-12f);
    const float gn = gv * (4.0f / rn);
    float am = fabsf(gn);
    {
      float o;
      o = __shfl_xor(am, 1, 64); am = fmaxf(am, o);
      o = __shfl_xor(am, 2, 64); am = fmaxf(am, o);
      o = __shfl_xor(am, 4, 64); am = fmaxf(am, o);
      o = __shfl_xor(am, 8, 64); am = fmaxf(am, o);
    }
    const float mc2 = fmaxf(am, 1e-5f);
    const float xs2 = 127.0f / mc2;
    const float s2  = w2 / xs2;

    unsigned sh = q8(gn, xs2) << ((l & 3) * 8);
    sh |= (unsigned)__shfl_xor((int)sh, 1, 64);
    sh |= (unsigned)__shfl_xor((int)sh, 2, 64);
    const unsigned wa = (unsigned)__shfl_xor((int)sh, 4, 64);
    const unsigned wb = (unsigned)__shfl_xor((int)sh, 8, 64);
    const unsigned wc = (unsigned)__shfl_xor((int)sh, 12, 64);
    if (l == 0) {
      qls[ws][t] = make_uint4(sh, wa, wb, wc);
      sls[ws][t] = s2;
    }
  }

  // ---- phase B: Wv from L2 (coalesced wv4t), rolled m-loop ----
  // qls/sls are wave-private: same-wave ds_write -> ds_read is program-order.
  uint4 q[TPW]; float s2v[TPW];
#pragma unroll
  for (int i = 0; i < TPW; ++i) { q[i] = qls[ws][i]; s2v[i] = sls[ws][i]; }

#pragma unroll 1
  for (int m = 0; m < 8; ++m) {
    const uint4 wv0 = wvt[(m * 4 + 0) * 64 + l];
    const uint4 wv1 = wvt[(m * 4 + 1) * 64 + l];
    const uint4 wv2 = wvt[(m * 4 + 2) * 64 + l];
    const uint4 wv3 = wvt[(m * 4 + 3) * 64 + l];
#pragma unroll
    for (int t = 0; t < TPW; ++t) {
      float h[4];
      {
        int d = dot4(q[t].x, wv0.x, 0);
        d = dot4(q[t].y, wv0.y, d); d = dot4(q[t].z, wv0.z, d);
        d = dot4(q[t].w, wv0.w, d); h[0] = (float)d * s2v[t];
      }
      {
        int d = dot4(q[t].x, wv1.x, 0);
        d = dot4(q[t].y, wv1.y, d); d = dot4(q[t].z, wv1.z, d);
        d = dot4(q[t].w, wv1.w, d); h[1] = (float)d * s2v[t];
      }
      {
        int d = dot4(q[t].x, wv2.x, 0);
        d = dot4(q[t].y, wv2.y, d); d = dot4(q[t].z, wv2.z, d);
        d = dot4(q[t].w, wv2.w, d); h[2] = (float)d * s2v[t];
      }
      {
        int d = dot4(q[t].x, wv3.x, 0);
        d = dot4(q[t].y, wv3.y, d); d = dot4(q[t].z, wv3.z, d);
        d = dot4(q[t].w, wv3.w, d); h[3] = (float)d * s2v[t];
      }
      *(float4*)(out + (size_t)(t0 + t) * 2048 + m * 256 + l * 4) =
          make_float4(h[0], h[1], h[2], h[3]);
    }
  }
}

extern "C" void kernel_launch(void* const* d_in, const int* in_sizes, int n_in,
                              void* d_out, int out_size, void* d_ws, size_t ws_size,
                              hipStream_t stream) {
  const float* x  = (const float*)d_in[0];
  const float* Wk = (const float*)d_in[1];
  const float* Wv = (const float*)d_in[2];

  const int tokens = in_sizes[0] / DIN;  // 16384

  char* ws = (char*)d_ws;
  float*    hdr = (float*)(ws + HDR_OFF);
  unsigned* wk4 = (unsigned*)(ws + WK4_OFF);
  unsigned* wv4 = (unsigned*)(ws + WV4_OFF);

  k_prep<<<40, 256, 0, stream>>>(Wk, Wv, hdr, wk4, wv4);
  k_main<<<tokens / (TPW * WPB), 256, 0, stream>>>(x, hdr, wk4, wv4, (float*)d_out);
}

// Round 5
// 274.053 us; speedup vs baseline: 1.0866x; 1.0866x over previous
//
#include <hip/hip_runtime.h>

#define DIN   2048
#define DOUT  2048
#define NP    16

// ws layout (byte offsets)
#define HDR_OFF   0                        // 2 floats: w1, w2
#define WK4_OFF   256                      // 8192 u32 (32 KB) ternary Wk (flat p-major)
#define WV4_OFF   (WK4_OFF + 32768)        // 2048 uint4 (32 KB) ternary Wv (transposed)
#define XSW_OFF   (WV4_OFF + 32768)        // 16384 floats: per-token xs
#define XQ_OFF    (XSW_OFF + 65536)        // 16384 x 2048 int8 (33.5 MB)
#define Q2_OFF    (XQ_OFF + 33554432)      // 16384 uint4
#define S2_OFF    (Q2_OFF + 262144)        // 16384 floats

static __device__ __forceinline__ int dot4(unsigned a, unsigned b, int c) {
#if defined(__has_builtin) && __has_builtin(__builtin_amdgcn_sdot4)
  return __builtin_amdgcn_sdot4((int)a, (int)b, c, false);
#else
  c += (int)(signed char)(a & 0xffu)        * (int)(signed char)(b & 0xffu);
  c += (int)(signed char)((a >> 8) & 0xffu) * (int)(signed char)((b >> 8) & 0xffu);
  c += (int)(signed char)((a >> 16) & 0xffu)* (int)(signed char)((b >> 16) & 0xffu);
  c += (int)(signed char)(a >> 24)          * (int)(signed char)(b >> 24);
  return c;
#endif
}

// fma-magic int8 quantize: low byte of (f*xs + 1.5*2^23) = round-to-even(f*xs)
static __device__ __forceinline__ unsigned qmagic(float f, float xs) {
  return __float_as_uint(fmaf(f, xs, 12582912.0f)) & 0xffu;
}

// reference-exact double-rounded quantize (epilogue 16-value re-quant)
static __device__ __forceinline__ unsigned q8(float f, float xs) {
  float t = f * xs;
  float r = rintf(t);
  r = fmaxf(-128.0f, fminf(127.0f, r));
  return ((unsigned)(int)r) & 0xffu;
}

// ---------------------------------------------------------------------------
// k_prep: fused reduce+pack, 40 blocks (unchanged semantics -> bitwise-same
// scales). Blocks 0-31 pack Wk flat; 32-39 pack Wv into transposed layout
// wv4t[(m*4+j)*64 + lr] = ternary row o, o = m*256 + lr*4 + j.
// ---------------------------------------------------------------------------
__global__ __launch_bounds__(256) void k_prep(
    const float* __restrict__ Wk, const float* __restrict__ Wv,
    float* __restrict__ hdr, unsigned* __restrict__ wk4, unsigned* __restrict__ wv4)
{
  __shared__ float red[8][256];
  const int tid = threadIdx.x, b = blockIdx.x;
  const int isV = (b >= 32);
  const float4* W = (const float4*)(isV ? Wv : Wk);

  float4 own = make_float4(0.f, 0.f, 0.f, 0.f);
#pragma unroll
  for (int lb = 0; lb < 8; ++lb) {
    float s = 0.f;
#pragma unroll
    for (int i = 0; i < 4; ++i) {
      float4 v = W[lb * 1024 + i * 256 + tid];
      if (!isV && (lb * 4 + i) == b) own = v;
      s += fabsf(v.x) + fabsf(v.y) + fabsf(v.z) + fabsf(v.w);
    }
    red[lb][tid] = s;
  }
  __syncthreads();
#pragma unroll 1
  for (int o = 128; o > 0; o >>= 1) {
    if (tid < o) {
#pragma unroll
      for (int lb = 0; lb < 8; ++lb) red[lb][tid] += red[lb][tid + o];
    }
    __syncthreads();
  }
  float sum = 0.f;
#pragma unroll
  for (int lb = 0; lb < 8; ++lb) sum += red[lb][0];
  const float sc = fmaxf(sum * (1.0f / 32768.0f), 1e-5f);
  if (tid == 0 && (b == 0 || b == 32)) hdr[isV] = sc;

  if (!isV) {
    const int c = b * 256 + tid;
    unsigned pk = 0; const float* wp = &own.x;
#pragma unroll
    for (int j = 0; j < 4; ++j) {
      float r = rintf(wp[j] / sc);
      r = fmaxf(-1.0f, fminf(1.0f, r));
      pk |= (((unsigned)(int)r) & 0xffu) << (8 * j);
    }
    wk4[c] = pk;
  } else {
    const int o = (b - 32) * 256 + tid;
    unsigned u[4];
#pragma unroll
    for (int cc = 0; cc < 4; ++cc) {
      float4 w = ((const float4*)Wv)[o * 4 + cc];
      const float* wp = &w.x;
      unsigned pk = 0;
#pragma unroll
      for (int r = 0; r < 4; ++r) {
        float q = rintf(wp[r] / sc);
        q = fmaxf(-1.0f, fminf(1.0f, q));
        pk |= (((unsigned)(int)q) & 0xffu) << (8 * r);
      }
      u[cc] = pk;
    }
    const int m = o >> 8, r = o & 255, lr = r >> 2, j = r & 3;
    ((uint4*)wv4)[(m * 4 + j) * 64 + lr] = make_uint4(u[0], u[1], u[2], u[3]);
  }
}

// ---------------------------------------------------------------------------
// k_quant: pass 1. Wave per token (4 tokens/wave via loop), block = 16
// consecutive tokens. Read x coalesced, wave absmax (order-free), fma-magic
// quantize, write x_q ROW-MAJOR (coalesced dword stores) + xs.
// ~50 VGPR, 16 waves/CU, pure streaming: should run at read-BW roofline.
// ---------------------------------------------------------------------------
__global__ __launch_bounds__(256) void k_quant(
    const float* __restrict__ x, unsigned* __restrict__ xqw,
    float* __restrict__ xsw)
{
  const int tid = threadIdx.x, l = tid & 63, wv = tid >> 6;
  const long tb = (long)blockIdx.x * 16 + wv * 4;
  const float4* xf = (const float4*)x;

#pragma unroll 1
  for (int i = 0; i < 4; ++i) {
    const long tok = tb + i;
    float4 a[8];
#pragma unroll
    for (int c = 0; c < 8; ++c) a[c] = xf[tok * 512 + c * 64 + l];

    float mx = 0.0f;
#pragma unroll
    for (int c = 0; c < 8; ++c) {
      mx = fmaxf(mx, fabsf(a[c].x)); mx = fmaxf(mx, fabsf(a[c].y));
      mx = fmaxf(mx, fabsf(a[c].z)); mx = fmaxf(mx, fabsf(a[c].w));
    }
#pragma unroll
    for (int d = 1; d < 64; d <<= 1) mx = fmaxf(mx, __shfl_xor(mx, d, 64));
    const float mcl = fmaxf(mx, 1e-5f);
    const float xs  = 127.0f / mcl;

#pragma unroll
    for (int c = 0; c < 8; ++c) {
      const unsigned q = qmagic(a[c].x, xs) | (qmagic(a[c].y, xs) << 8)
                       | (qmagic(a[c].z, xs) << 16) | (qmagic(a[c].w, xs) << 24);
      xqw[tok * 512 + c * 64 + l] = q;
    }
    if (l == 0) xsw[tok] = xs;
  }
}

// ---------------------------------------------------------------------------
// k_mid: pass 2. Block = 256 threads = 4 waves, 32 tokens. Wave wv covers
// k-quarter wv; lane = (token t = l>>1, k-half h = l&1) -> per lane 64 words.
// Wk from 32 KB linear LDS: per read only 2 distinct addresses across the
// wave (h) -> broadcast, conflict-free, NO swizzle needed. acc[16] int
// (exact, any order). Cross-wave reduce via padded LDS, then 32 lanes do the
// full epilogue IN-LANE, replicating the reference shuffle trees exactly:
// norm = ((t1 pairs) -> t2 -> t3 -> sum) identical bracketing; max order-free.
// ---------------------------------------------------------------------------
__global__ __launch_bounds__(256) void k_mid(
    const unsigned* __restrict__ xq, const float* __restrict__ xsw,
    const unsigned* __restrict__ wk4, const float* __restrict__ hdr,
    uint4* __restrict__ q2w, float* __restrict__ s2w)
{
  __shared__ unsigned wkS[8192];     // 32 KB, linear
  __shared__ int accS[4][32][17];    // +1 pad: bank-conflict-free

  const int tid = threadIdx.x, l = tid & 63, wv = tid >> 6;
  const long t0 = (long)blockIdx.x * 32;

#pragma unroll 1
  for (int i = 0; i < 32; ++i) wkS[i * 256 + tid] = wk4[i * 256 + tid];
  __syncthreads();

  const int t = l >> 1, h = l & 1;
  const unsigned* xrow = xq + (t0 + t) * 512 + wv * 128 + h * 64;
  const unsigned* wbase = wkS + wv * 128 + h * 64;

  int acc[16];
#pragma unroll
  for (int p = 0; p < 16; ++p) acc[p] = 0;

#pragma unroll 2
  for (int c4 = 0; c4 < 16; ++c4) {
    const uint4 xv = *(const uint4*)(xrow + c4 * 4);
#pragma unroll
    for (int p = 0; p < 16; ++p) {
      const uint4 w = *(const uint4*)(wbase + p * 512 + c4 * 4);
      int d = acc[p];
      d = dot4(xv.x, w.x, d); d = dot4(xv.y, w.y, d);
      d = dot4(xv.z, w.z, d); d = dot4(xv.w, w.w, d);
      acc[p] = d;
    }
  }

  // combine k-halves (int, exact)
#pragma unroll
  for (int p = 0; p < 16; ++p) acc[p] += __shfl_xor(acc[p], 1, 64);
  if (h == 0) {
#pragma unroll
    for (int p = 0; p < 16; ++p) accS[wv][t][p] = acc[p];
  }
  __syncthreads();

  if (tid < 32) {
    const long tok = t0 + tid;
    int r[16];
#pragma unroll
    for (int p = 0; p < 16; ++p)
      r[p] = ((accS[0][tid][p] + accS[1][tid][p]) + accS[2][tid][p]) + accS[3][tid][p];

    const float xs = xsw[tok];
    const float s1 = hdr[0] / xs;

    float g[16];
#pragma unroll
    for (int p = 0; p < 16; ++p) {
      const float fa = (float)r[p] * s1;
      g[p] = 0.5f * fa * (1.0f + erff(fa * 0.70710678118654752f));
    }
    // exact replication of the reference shuffle-tree bracketing
    float t1[8], t2[4], t3[2];
#pragma unroll
    for (int j = 0; j < 8; ++j) t1[j] = g[2 * j] * g[2 * j] + g[2 * j + 1] * g[2 * j + 1];
#pragma unroll
    for (int j = 0; j < 4; ++j) t2[j] = t1[2 * j] + t1[2 * j + 1];
    t3[0] = t2[0] + t2[1]; t3[1] = t2[2] + t2[3];
    const float ssum = t3[0] + t3[1];

    const float rn  = fmaxf(sqrtf(ssum), 1e-12f);
    const float inv = 4.0f / rn;
    float gn[16]; float am = 0.0f;
#pragma unroll
    for (int p = 0; p < 16; ++p) { gn[p] = g[p] * inv; am = fmaxf(am, fabsf(gn[p])); }
    const float mc2 = fmaxf(am, 1e-5f);
    const float xs2 = 127.0f / mc2;
    const float s2  = hdr[1] / xs2;

    unsigned w[4];
#pragma unroll
    for (int j = 0; j < 4; ++j)
      w[j] = q8(gn[4 * j], xs2)            | (q8(gn[4 * j + 1], xs2) << 8)
           | (q8(gn[4 * j + 2], xs2) << 16) | (q8(gn[4 * j + 3], xs2) << 24);
    q2w[tok] = make_uint4(w[0], w[1], w[2], w[3]);
    s2w[tok] = s2;
  }
}

// ---------------------------------------------------------------------------
// k_out: pass 3. Block = 4 waves; block m-slice = blockIdx&7, token chunk =
// blockIdx>>3 (64 tokens, 16/wave). Per lane only 16 VGPR of Wv; q2/s2 are
// wave-uniform -> scalar loads. 16 sdot4 + 1 float4 store per token: pure
// write-streaming at full occupancy. Should run at write-BW roofline.
// ---------------------------------------------------------------------------
__global__ __launch_bounds__(256) void k_out(
    const uint4* __restrict__ wv4t, const uint4* __restrict__ q2w,
    const float* __restrict__ s2w, float* __restrict__ out)
{
  const int tid = threadIdx.x, l = tid & 63, wv = tid >> 6;
  const int m = blockIdx.x & 7;
  const long tb = (long)(blockIdx.x >> 3) * 64 + wv * 16;

  const uint4 w0 = wv4t[(m * 4 + 0) * 64 + l];
  const uint4 w1 = wv4t[(m * 4 + 1) * 64 + l];
  const uint4 w2 = wv4t[(m * 4 + 2) * 64 + l];
  const uint4 w3 = wv4t[(m * 4 + 3) * 64 + l];

#pragma unroll 1
  for (int i = 0; i < 16; ++i) {
    const long tok = tb + i;
    const uint4 q  = q2w[tok];
    const float s2 = s2w[tok];
    int d; float h0, h1, h2, h3;
    d = dot4(q.x, w0.x, 0); d = dot4(q.y, w0.y, d);
    d = dot4(q.z, w0.z, d); d = dot4(q.w, w0.w, d); h0 = (float)d * s2;
    d = dot4(q.x, w1.x, 0); d = dot4(q.y, w1.y, d);
    d = dot4(q.z, w1.z, d); d = dot4(q.w, w1.w, d); h1 = (float)d * s2;
    d = dot4(q.x, w2.x, 0); d = dot4(q.y, w2.y, d);
    d = dot4(q.z, w2.z, d); d = dot4(q.w, w2.w, d); h2 = (float)d * s2;
    d = dot4(q.x, w3.x, 0); d = dot4(q.y, w3.y, d);
    d = dot4(q.z, w3.z, d); d = dot4(q.w, w3.w, d); h3 = (float)d * s2;
    *(float4*)(out + (size_t)tok * 2048 + m * 256 + l * 4) =
        make_float4(h0, h1, h2, h3);
  }
}

extern "C" void kernel_launch(void* const* d_in, const int* in_sizes, int n_in,
                              void* d_out, int out_size, void* d_ws, size_t ws_size,
                              hipStream_t stream) {
  const float* x  = (const float*)d_in[0];
  const float* Wk = (const float*)d_in[1];
  const float* Wv = (const float*)d_in[2];

  const int tokens = in_sizes[0] / DIN;  // 16384

  char* ws = (char*)d_ws;
  float*    hdr = (float*)(ws + HDR_OFF);
  unsigned* wk4 = (unsigned*)(ws + WK4_OFF);
  unsigned* wv4 = (unsigned*)(ws + WV4_OFF);
  float*    xsw = (float*)(ws + XSW_OFF);
  unsigned* xqw = (unsigned*)(ws + XQ_OFF);
  uint4*    q2w = (uint4*)(ws + Q2_OFF);
  float*    s2w = (float*)(ws + S2_OFF);

  k_prep <<<40, 256, 0, stream>>>(Wk, Wv, hdr, wk4, wv4);
  k_quant<<<tokens / 16, 256, 0, stream>>>(x, xqw, xsw);
  k_mid  <<<tokens / 32, 256, 0, stream>>>(xqw, xsw, wk4, hdr, q2w, s2w);
  k_out  <<<(tokens / 64) * 8, 256, 0, stream>>>((const uint4*)wv4, q2w, s2w,
                                                 (float*)d_out);
}

// Round 6
// 259.862 us; speedup vs baseline: 1.1460x; 1.0546x over previous
//
#include <hip/hip_runtime.h>

#define DIN   2048
#define DOUT  2048
#define NP    16

// ws layout (byte offsets)
#define HDR_OFF   0                        // 2 floats: w1, w2
#define WKT_OFF   256                      // 8192 u32 (32 KB) ternary Wk, TRANSPOSED:
                                           //   uint4[c2*64 + q*16 + p] = Wk words p*512+q*128+c2*4..+3
#define WVT_OFF   (WKT_OFF + 32768)        // 2048 uint4 (32 KB) ternary Wv (transposed)
#define Q2_OFF    (WVT_OFF + 32768)        // 16384 uint4
#define S2_OFF    (Q2_OFF + 262144)        // 16384 floats

static __device__ __forceinline__ int dot4(unsigned a, unsigned b, int c) {
#if defined(__has_builtin) && __has_builtin(__builtin_amdgcn_sdot4)
  return __builtin_amdgcn_sdot4((int)a, (int)b, c, false);
#else
  c += (int)(signed char)(a & 0xffu)        * (int)(signed char)(b & 0xffu);
  c += (int)(signed char)((a >> 8) & 0xffu) * (int)(signed char)((b >> 8) & 0xffu);
  c += (int)(signed char)((a >> 16) & 0xffu)* (int)(signed char)((b >> 16) & 0xffu);
  c += (int)(signed char)(a >> 24)          * (int)(signed char)(b >> 24);
  return c;
#endif
}

// fma-magic int8 quantize: low byte of (f*xs + 1.5*2^23) = round-to-even(f*xs)
static __device__ __forceinline__ unsigned qmagic(float f, float xs) {
  return __float_as_uint(fmaf(f, xs, 12582912.0f)) & 0xffu;
}

// reference-exact double-rounded quantize (epilogue 16-value re-quant)
static __device__ __forceinline__ unsigned q8(float f, float xs) {
  float t = f * xs;
  float r = rintf(t);
  r = fmaxf(-128.0f, fminf(127.0f, r));
  return ((unsigned)(int)r) & 0xffu;
}

// ---------------------------------------------------------------------------
// k_prep: fused reduce+pack, 40 blocks. Scale computation identical op order
// as always -> bitwise-same sc. Blocks 0-31 pack Wk into the TRANSPOSED
// coalesced-stream layout; 32-39 pack Wv transposed (unchanged from R5).
// ---------------------------------------------------------------------------
__global__ __launch_bounds__(256) void k_prep(
    const float* __restrict__ Wk, const float* __restrict__ Wv,
    float* __restrict__ hdr, unsigned* __restrict__ wk4t, unsigned* __restrict__ wv4)
{
  __shared__ float red[8][256];
  const int tid = threadIdx.x, b = blockIdx.x;
  const int isV = (b >= 32);
  const float4* W = (const float4*)(isV ? Wv : Wk);

  float4 own = make_float4(0.f, 0.f, 0.f, 0.f);
#pragma unroll
  for (int lb = 0; lb < 8; ++lb) {
    float s = 0.f;
#pragma unroll
    for (int i = 0; i < 4; ++i) {
      float4 v = W[lb * 1024 + i * 256 + tid];
      if (!isV && (lb * 4 + i) == b) own = v;
      s += fabsf(v.x) + fabsf(v.y) + fabsf(v.z) + fabsf(v.w);
    }
    red[lb][tid] = s;
  }
  __syncthreads();
#pragma unroll 1
  for (int o = 128; o > 0; o >>= 1) {
    if (tid < o) {
#pragma unroll
      for (int lb = 0; lb < 8; ++lb) red[lb][tid] += red[lb][tid + o];
    }
    __syncthreads();
  }
  float sum = 0.f;
#pragma unroll
  for (int lb = 0; lb < 8; ++lb) sum += red[lb][0];
  const float sc = fmaxf(sum * (1.0f / 32768.0f), 1e-5f);
  if (tid == 0 && (b == 0 || b == 32)) hdr[isV] = sc;

  if (!isV) {
    const int c = b * 256 + tid;          // flat Wk word index p*512 + kw
    unsigned pk = 0; const float* wp = &own.x;
#pragma unroll
    for (int j = 0; j < 4; ++j) {
      float r = rintf(wp[j] / sc);
      r = fmaxf(-1.0f, fminf(1.0f, r));
      pk |= (((unsigned)(int)r) & 0xffu) << (8 * j);
    }
    const int p = c >> 9, kw = c & 511;
    const int q = kw >> 7, c2 = (kw >> 2) & 31, sub = kw & 3;
    wk4t[c2 * 256 + q * 64 + p * 4 + sub] = pk;
  } else {
    const int o = (b - 32) * 256 + tid;   // Wv row
    unsigned u[4];
#pragma unroll
    for (int cc = 0; cc < 4; ++cc) {
      float4 w = ((const float4*)Wv)[o * 4 + cc];
      const float* wp = &w.x;
      unsigned pk = 0;
#pragma unroll
      for (int r = 0; r < 4; ++r) {
        float q = rintf(wp[r] / sc);
        q = fmaxf(-1.0f, fminf(1.0f, q));
        pk |= (((unsigned)(int)q) & 0xffu) << (8 * r);
      }
      u[cc] = pk;
    }
    const int m = o >> 8, r = o & 255, lr = r >> 2, j = r & 3;
    ((uint4*)wv4)[(m * 4 + j) * 64 + lr] = make_uint4(u[0], u[1], u[2], u[3]);
  }
}

// ---------------------------------------------------------------------------
// kA2: phase A, one wave per 2 tokens (8192 waves, 2048 blocks) = max TLP,
// minimal per-wave serial chain. Per token: 8 coalesced float4 loads, absmax
// (in-lane + 6 shfl, same tree as always), qmagic quant -> padded LDS
// (stride 136 words per k-quarter: q-groups on disjoint banks, b128 reads
// conflict-free). Dot: lane owns (p=l&15, q=l>>4); Wk streamed COALESCED
// from L2 via wkT[c2*64+l] (same 32 KB for every wave -> chip-hot), 2 tokens
// share each Wk fragment. Quarter-sum via int shfl_xor(16,32) (exact).
// Epilogue per token, all lanes redundant — verbatim R4 trees (bitwise-same).
// ---------------------------------------------------------------------------
__global__ __launch_bounds__(256) void kA2(
    const float* __restrict__ x, const float* __restrict__ hdr,
    const unsigned* __restrict__ wk4t, uint4* __restrict__ q2w,
    float* __restrict__ s2w)
{
  const int tid = threadIdx.x, l = tid & 63, wv = tid >> 6;
  const long t0 = (long)blockIdx.x * 8 + wv * 2;

  __shared__ unsigned xqs[4][2][544];   // [wave][token][4 quarters x 136 words]

  const float w1 = hdr[0], w2 = hdr[1];
  const float4* xf  = (const float4*)x;
  const uint4*  wkT = (const uint4*)wk4t;

  float s1v[2];
#pragma unroll
  for (int tt = 0; tt < 2; ++tt) {
    const long tok = t0 + tt;
    float4 a[8];
#pragma unroll
    for (int c = 0; c < 8; ++c) a[c] = xf[tok * 512 + c * 64 + l];

    float mx = 0.0f;
#pragma unroll
    for (int c = 0; c < 8; ++c) {
      mx = fmaxf(mx, fabsf(a[c].x)); mx = fmaxf(mx, fabsf(a[c].y));
      mx = fmaxf(mx, fabsf(a[c].z)); mx = fmaxf(mx, fabsf(a[c].w));
    }
#pragma unroll
    for (int d = 1; d < 64; d <<= 1) mx = fmaxf(mx, __shfl_xor(mx, d, 64));
    const float mcl = fmaxf(mx, 1e-5f);
    const float xs  = 127.0f / mcl;
    s1v[tt] = w1 / xs;

#pragma unroll
    for (int c = 0; c < 8; ++c) {
      const unsigned qv = qmagic(a[c].x, xs) | (qmagic(a[c].y, xs) << 8)
                        | (qmagic(a[c].z, xs) << 16) | (qmagic(a[c].w, xs) << 24);
      // word f = c*64+l -> quarter q=c>>1, offset (c&1)*64+l
      xqs[wv][tt][(c >> 1) * 136 + (c & 1) * 64 + l] = qv;
    }
  }

  // ---- dots: lane (p=l&15, q=l>>4); both tokens share the Wk stream ----
  const unsigned* xb0 = &xqs[wv][0][(l >> 4) * 136];
  const unsigned* xb1 = &xqs[wv][1][(l >> 4) * 136];
  int ac0[4] = {0, 0, 0, 0}, ac1[4] = {0, 0, 0, 0};
#pragma unroll
  for (int c2 = 0; c2 < 32; ++c2) {
    const uint4 w  = wkT[c2 * 64 + l];                 // coalesced, L2-hot
    const uint4 x0 = *(const uint4*)(xb0 + c2 * 4);    // 16-lane broadcast
    const uint4 x1 = *(const uint4*)(xb1 + c2 * 4);
    int d0 = ac0[c2 & 3];
    d0 = dot4(x0.x, w.x, d0); d0 = dot4(x0.y, w.y, d0);
    d0 = dot4(x0.z, w.z, d0); d0 = dot4(x0.w, w.w, d0);
    ac0[c2 & 3] = d0;
    int d1 = ac1[c2 & 3];
    d1 = dot4(x1.x, w.x, d1); d1 = dot4(x1.y, w.y, d1);
    d1 = dot4(x1.z, w.z, d1); d1 = dot4(x1.w, w.w, d1);
    ac1[c2 & 3] = d1;
  }
  int rrv[2];
  rrv[0] = (ac0[0] + ac0[1]) + (ac0[2] + ac0[3]);
  rrv[1] = (ac1[0] + ac1[1]) + (ac1[2] + ac1[3]);

#pragma unroll
  for (int tt = 0; tt < 2; ++tt) {
    int rr = rrv[tt];
    rr += __shfl_xor(rr, 16, 64);
    rr += __shfl_xor(rr, 32, 64);

    // ---- per-token epilogue, all lanes redundant (p = l&15) — R4 verbatim ----
    const float fa = (float)rr * s1v[tt];
    const float gv = 0.5f * fa * (1.0f + erff(fa * 0.70710678118654752f));
    float ss = gv * gv;
    ss += __shfl_xor(ss, 1, 64); ss += __shfl_xor(ss, 2, 64);
    ss += __shfl_xor(ss, 4, 64); ss += __shfl_xor(ss, 8, 64);
    const float rn = fmaxf(sqrtf(ss), 1e-12f);
    const float gn = gv * (4.0f / rn);
    float am = fabsf(gn);
    {
      float o;
      o = __shfl_xor(am, 1, 64); am = fmaxf(am, o);
      o = __shfl_xor(am, 2, 64); am = fmaxf(am, o);
      o = __shfl_xor(am, 4, 64); am = fmaxf(am, o);
      o = __shfl_xor(am, 8, 64); am = fmaxf(am, o);
    }
    const float mc2 = fmaxf(am, 1e-5f);
    const float xs2 = 127.0f / mc2;
    const float s2  = w2 / xs2;

    unsigned sh = q8(gn, xs2) << ((l & 3) * 8);
    sh |= (unsigned)__shfl_xor((int)sh, 1, 64);
    sh |= (unsigned)__shfl_xor((int)sh, 2, 64);
    const unsigned wa = (unsigned)__shfl_xor((int)sh, 4, 64);
    const unsigned wb = (unsigned)__shfl_xor((int)sh, 8, 64);
    const unsigned wc = (unsigned)__shfl_xor((int)sh, 12, 64);
    if (l == 0) {
      q2w[t0 + tt] = make_uint4(sh, wa, wb, wc);
      s2w[t0 + tt] = s2;
    }
  }
}

// ---------------------------------------------------------------------------
// k_out: phase B. Block = 4 waves; m-slice = blockIdx&7, token chunk =
// blockIdx>>3 (64 tokens, 16/wave). 16 VGPR of Wv per lane; q2/s2 wave-
// uniform broadcast loads; unroll 2 so next token's q2 load pipelines under
// this token's dots. Pure write-streaming at full occupancy.
// ---------------------------------------------------------------------------
__global__ __launch_bounds__(256) void k_out(
    const uint4* __restrict__ wv4t, const uint4* __restrict__ q2w,
    const float* __restrict__ s2w, float* __restrict__ out)
{
  const int tid = threadIdx.x, l = tid & 63, wv = tid >> 6;
  const int m = blockIdx.x & 7;
  const long tb = (long)(blockIdx.x >> 3) * 64 + wv * 16;

  const uint4 w0 = wv4t[(m * 4 + 0) * 64 + l];
  const uint4 w1 = wv4t[(m * 4 + 1) * 64 + l];
  const uint4 w2 = wv4t[(m * 4 + 2) * 64 + l];
  const uint4 w3 = wv4t[(m * 4 + 3) * 64 + l];

#pragma unroll 2
  for (int i = 0; i < 16; ++i) {
    const long tok = tb + i;
    const uint4 q  = q2w[tok];
    const float s2 = s2w[tok];
    int d; float h0, h1, h2, h3;
    d = dot4(q.x, w0.x, 0); d = dot4(q.y, w0.y, d);
    d = dot4(q.z, w0.z, d); d = dot4(q.w, w0.w, d); h0 = (float)d * s2;
    d = dot4(q.x, w1.x, 0); d = dot4(q.y, w1.y, d);
    d = dot4(q.z, w1.z, d); d = dot4(q.w, w1.w, d); h1 = (float)d * s2;
    d = dot4(q.x, w2.x, 0); d = dot4(q.y, w2.y, d);
    d = dot4(q.z, w2.z, d); d = dot4(q.w, w2.w, d); h2 = (float)d * s2;
    d = dot4(q.x, w3.x, 0); d = dot4(q.y, w3.y, d);
    d = dot4(q.z, w3.z, d); d = dot4(q.w, w3.w, d); h3 = (float)d * s2;
    *(float4*)(out + (size_t)tok * 2048 + m * 256 + l * 4) =
        make_float4(h0, h1, h2, h3);
  }
}

extern "C" void kernel_launch(void* const* d_in, const int* in_sizes, int n_in,
                              void* d_out, int out_size, void* d_ws, size_t ws_size,
                              hipStream_t stream) {
  const float* x  = (const float*)d_in[0];
  const float* Wk = (const float*)d_in[1];
  const float* Wv = (const float*)d_in[2];

  const int tokens = in_sizes[0] / DIN;  // 16384

  char* ws = (char*)d_ws;
  float*    hdr  = (float*)(ws + HDR_OFF);
  unsigned* wk4t = (unsigned*)(ws + WKT_OFF);
  unsigned* wv4  = (unsigned*)(ws + WVT_OFF);
  uint4*    q2w  = (uint4*)(ws + Q2_OFF);
  float*    s2w  = (float*)(ws + S2_OFF);

  k_prep<<<40, 256, 0, stream>>>(Wk, Wv, hdr, wk4t, wv4);
  kA2   <<<tokens / 8, 256, 0, stream>>>(x, hdr, wk4t, q2w, s2w);
  k_out <<<(tokens / 64) * 8, 256, 0, stream>>>((const uint4*)wv4, q2w, s2w,
                                                (float*)d_out);
}